// Round 3
// baseline (37.103 us; speedup 1.0000x reference)
//
#include <hip/hip_runtime.h>

#define PH 7
#define PW 7
#define CPB 8            // channels per block
#define RROWS 20         // max region rows (box <600px/32 -> <=19, +1 ceil slack)

__global__ __launch_bounds__(256) void roipool_kernel(
    const float* __restrict__ feat,
    const float* __restrict__ rois,
    float* __restrict__ out,
    int C, int H, int W) {

    const int cg  = blockIdx.x;       // channel group
    const int r   = blockIdx.y;       // ROI index
    const int c0  = cg * CPB;
    const int tid = threadIdx.x;

    __shared__ float lds[CPB][RROWS][64];   // full-width rows: no column windowing

    // ---- block-uniform ROI math: VERBATIM from the passing R1 kernel ----
    const float RATIO = 1.0f / 32.0f;
    const int   b  = (int)rois[r * 5 + 0];
    const float x0 = fminf(fmaxf(floorf(rois[r * 5 + 1] * RATIO), 0.0f), (float)W);
    const float y0 = fminf(fmaxf(floorf(rois[r * 5 + 2] * RATIO), 0.0f), (float)H);
    const float x1 = fminf(fmaxf(floorf(rois[r * 5 + 3] * RATIO), 0.0f), (float)W);
    const float y1 = fminf(fmaxf(floorf(rois[r * 5 + 4] * RATIO), 0.0f), (float)H);
    const bool valid = (x1 > x0) && (y1 > y0);
    const float bin_h = (y1 - y0) * (1.0f / PH);
    const float bin_w = (x1 - x0) * (1.0f / PW);

    // staged row window = [ry0, ry0 + RHs), same expressions as per-bin i=0 / i=7
    int ry0 = (int)(y0 + floorf(0.0f * bin_h));     ry0 = min(max(ry0, 0), H);
    int rye = (int)(y0 + ceilf((float)PH * bin_h)); rye = min(max(rye, 0), H);
    const int RHs = min(rye - ry0, RROWS);

    // ---- stage full rows into LDS (straight copy, no clamps) ----
    const int Wf4 = W >> 2;   // 16 float4 per row
    if (valid && RHs > 0) {
        for (int k = tid; k < CPB * RROWS * Wf4; k += 256) {   // 2560 items, 10 iters
            const int c_l = k / (RROWS * Wf4);
            const int rem = k % (RROWS * Wf4);
            const int y   = rem / Wf4;
            const int x4  = rem % Wf4;
            if (y < RHs) {
                const float4 v = *reinterpret_cast<const float4*>(
                    feat + (((size_t)b * C + c0 + c_l) * H + (ry0 + y)) * (size_t)W + (x4 * 4));
                *reinterpret_cast<float4*>(&lds[c_l][y][x4 * 4]) = v;
            }
        }
    }
    __syncthreads();

    // ---- compute 49 bins per channel ----
    for (int o = tid; o < CPB * PH * PW; o += 256) {          // 392 items
        const int c_l = o / (PH * PW);
        const int ij  = o % (PH * PW);
        const int i   = ij / PW;
        const int j   = ij % PW;

        int ys = (int)(y0 + floorf((float)i * bin_h));
        int ye = (int)(y0 + ceilf((float)(i + 1) * bin_h));
        int xs = (int)(x0 + floorf((float)j * bin_w));
        int xe = (int)(x0 + ceilf((float)(j + 1) * bin_w));
        ys = min(max(ys, 0), H);
        ye = min(max(ye, 0), H);
        xs = min(max(xs, 0), W);
        xe = min(max(xe, 0), W);
        const bool ok = valid && (ye > ys) && (xe > xs);

        float m = -INFINITY;
        if (ok) {
            if (ys >= ry0 && ye <= ry0 + RHs) {
                // fast path: rows are staged (expected always)
                for (int y = ys; y < ye; ++y)
                    for (int x = xs; x < xe; ++x)
                        m = fmaxf(m, lds[c_l][y - ry0][x]);
            } else {
                // fallback: direct global reads (exact R1 path)
                const float* base = feat + ((size_t)b * C + c0 + c_l) * (size_t)(H * W);
                for (int y = ys; y < ye; ++y)
                    for (int x = xs; x < xe; ++x)
                        m = fmaxf(m, base[y * W + x]);
            }
        }
        out[((size_t)r * C + c0 + c_l) * (PH * PW) + ij] = ok ? m : 0.0f;
    }
}

extern "C" void kernel_launch(void* const* d_in, const int* in_sizes, int n_in,
                              void* d_out, int out_size, void* d_ws, size_t ws_size,
                              hipStream_t stream) {
    const float* feat = (const float*)d_in[0];
    const float* rois = (const float*)d_in[1];
    float* out = (float*)d_out;

    const int R = in_sizes[1] / 5;       // 128
    const int C = 256, H = 64, W = 64;   // per reference setup (N=4)

    dim3 grid(C / CPB, R);               // 32 x 128 = 4096 blocks
    roipool_kernel<<<grid, 256, 0, stream>>>(feat, rois, out, C, H, W);
}

// Round 4
// 23.444 us; speedup vs baseline: 1.5826x; 1.5826x over previous
//
#include <hip/hip_runtime.h>

#define PH 7
#define PW 7
#define CPB 8            // channels per block
#define RROWS 20         // max region rows: box<600px/32 -> Dy<=19, +1 ceil slack
#define RF4 6            // float4s per staged row
#define RCOLS (RF4 * 4)  // 24 cols: Dx<=19 +1 ceil slack +3 align slack = 23 < 24

__global__ __launch_bounds__(256) void roipool_kernel(
    const float* __restrict__ feat,
    const float* __restrict__ rois,
    float* __restrict__ out,
    int C, int H, int W) {

    const int cg  = blockIdx.x;       // channel group
    const int r   = blockIdx.y;       // ROI index
    const int c0  = cg * CPB;
    const int tid = threadIdx.x;

    __shared__ float lds[CPB][RROWS][RCOLS];   // 15360 B

    // ---- block-uniform ROI math: VERBATIM from the passing R1 kernel ----
    const float RATIO = 1.0f / 32.0f;
    const int   b  = (int)rois[r * 5 + 0];
    const float x0 = fminf(fmaxf(floorf(rois[r * 5 + 1] * RATIO), 0.0f), (float)W);
    const float y0 = fminf(fmaxf(floorf(rois[r * 5 + 2] * RATIO), 0.0f), (float)H);
    const float x1 = fminf(fmaxf(floorf(rois[r * 5 + 3] * RATIO), 0.0f), (float)W);
    const float y1 = fminf(fmaxf(floorf(rois[r * 5 + 4] * RATIO), 0.0f), (float)H);
    const bool valid = (x1 > x0) && (y1 > y0);
    const float bin_h = (y1 - y0) * (1.0f / PH);
    const float bin_w = (x1 - x0) * (1.0f / PW);

    // staged window: rows [ry0, ry0+RHs), cols [rx0a, rx0a+RCOLS)
    int ry0 = (int)(y0 + floorf(0.0f * bin_h));     ry0 = min(max(ry0, 0), H);
    int rye = (int)(y0 + ceilf((float)PH * bin_h)); rye = min(max(rye, 0), H);
    int rx0 = (int)(x0 + floorf(0.0f * bin_w));     rx0 = min(max(rx0, 0), W);
    const int RHs  = min(rye - ry0, RROWS);
    const int rx0a = rx0 & ~3;                 // 16B-aligned column base
    const int Wf4  = W >> 2;
    const int x4base = rx0a >> 2;

    // ---- stage windowed region into LDS (float4, coalesced) ----
    if (valid && RHs > 0) {
        for (int k = tid; k < CPB * RROWS * RF4; k += 256) {   // 960 items
            const int c_l = k / (RROWS * RF4);
            const int rem = k % (RROWS * RF4);
            const int y   = rem / RF4;
            const int x4  = rem % RF4;
            if (y < RHs) {
                const int x4g = min(x4base + x4, Wf4 - 1);     // stay inside the row
                const float4 v = *reinterpret_cast<const float4*>(
                    feat + (((size_t)b * C + c0 + c_l) * H + (ry0 + y)) * (size_t)W + (x4g << 2));
                *reinterpret_cast<float4*>(&lds[c_l][y][x4 << 2]) = v;
            }
        }
    }
    __syncthreads();

    // ---- compute 49 bins per channel ----
    for (int o = tid; o < CPB * PH * PW; o += 256) {          // 392 items
        const int c_l = o / (PH * PW);
        const int ij  = o % (PH * PW);
        const int i   = ij / PW;
        const int j   = ij % PW;

        int ys = (int)(y0 + floorf((float)i * bin_h));
        int ye = (int)(y0 + ceilf((float)(i + 1) * bin_h));
        int xs = (int)(x0 + floorf((float)j * bin_w));
        int xe = (int)(x0 + ceilf((float)(j + 1) * bin_w));
        ys = min(max(ys, 0), H);
        ye = min(max(ye, 0), H);
        xs = min(max(xs, 0), W);
        xe = min(max(xe, 0), W);
        const bool ok = valid && (ye > ys) && (xe > xs);

        float m = -INFINITY;
        if (ok) {
            const bool staged = (ys >= ry0) && (ye <= ry0 + RHs) &&
                                (xs >= rx0a) && (xe - rx0a <= RCOLS);
            if (staged) {
                // fast path (expected always): window proven to hold exact columns
                for (int y = ys; y < ye; ++y)
                    for (int x = xs; x < xe; ++x)
                        m = fmaxf(m, lds[c_l][y - ry0][x - rx0a]);
            } else {
                // fallback: direct global reads (exact R1 path)
                const float* base = feat + ((size_t)b * C + c0 + c_l) * (size_t)(H * W);
                for (int y = ys; y < ye; ++y)
                    for (int x = xs; x < xe; ++x)
                        m = fmaxf(m, base[y * W + x]);
            }
        }
        out[((size_t)r * C + c0 + c_l) * (PH * PW) + ij] = ok ? m : 0.0f;
    }
}

extern "C" void kernel_launch(void* const* d_in, const int* in_sizes, int n_in,
                              void* d_out, int out_size, void* d_ws, size_t ws_size,
                              hipStream_t stream) {
    const float* feat = (const float*)d_in[0];
    const float* rois = (const float*)d_in[1];
    float* out = (float*)d_out;

    const int R = in_sizes[1] / 5;       // 128
    const int C = 256, H = 64, W = 64;   // per reference setup (N=4)

    dim3 grid(C / CPB, R);               // 32 x 128 = 4096 blocks
    roipool_kernel<<<grid, 256, 0, stream>>>(feat, rois, out, C, H, W);
}